// Round 6
// baseline (94.528 us; speedup 1.0000x reference)
//
#include <hip/hip_runtime.h>
#include <stdint.h>

#define NQ 12
#define DIM 4096
#define NLAYERS 6
#define TPB 256

typedef float v2f __attribute__((ext_vector_type(2)));

// ---------------------------------------------------------------------------
// Circuit algebra (rounds 4/5): all 72 rotations are register gates on a
// 4-bit local window; 17 GF(2)-linear gather passes re-window and fold the
// CNOT networks. Each pass has a compile-time conflict-free LDS layout
// Lambda: write addr = Lambda(k), read addr = Lambda(M(k)), with bank rows
// full-rank on the lane quarter-span and its M-image.
// Round 6 change: SINGLE-buffered 32 KB exchange (2 barriers/pass) =>
// ~34 KB LDS/block => 4 blocks/CU (was 2) => 4 waves/SIMD latency hiding.
// ---------------------------------------------------------------------------
struct Pass_t {
    uint32_t WT[8];    // Lambda columns for thread bits (k bits 4..11)
    uint32_t WL[16];   // Lambda image of local nibble l
    uint32_t RT[8];    // (Lambda o M) columns for thread bits
    uint32_t RL[16];   // (Lambda o M) image of local nibble l
};
struct CK_t {
    Pass_t PG2, PG3;       // fixed window-swap passes
    Pass_t P1[NLAYERS];    // per-layer rebase passes (index 1..5 used)
    uint32_t frow[NQ];     // epilogue sign rows
};

constexpr uint32_t G2f(uint32_t k){ return ((k&15u)<<8) | (k&0xF0u) | ((k>>8)&15u); }
constexpr uint32_t G3f(uint32_t k){ return ((k&15u)<<4) | ((k>>4)&15u) | (k&0xF00u); }

constexpr uint32_t ech_reduce(const uint32_t* v, int n, uint32_t x){
    bool ch = true;
    while (ch) {
        ch = false;
        for (int i = 0; i < n; i++)
            if (v[i] && (x ^ v[i]) < x) { x ^= v[i]; ch = true; }
    }
    return x;
}

constexpr Pass_t build_pass(const uint32_t* Mc) {
    Pass_t P{};
    uint32_t rows[12]{}; int nr = 0;
    {   // greedy bank rows: rank 4 on {e4..e7} and on {Mc[4]..Mc[7]}
        uint32_t e1[4]{}, e2[4]{}; int n1 = 0, n2 = 0;
        for (int step = 0; step < 4; step++) {
            bool found = false;
            for (int pc = 1; pc <= 3 && !found; pc++) {
                for (int a = 0; a < 12 && !found; a++)
                for (int b = (pc >= 2 ? a + 1 : 12); (pc >= 2 ? b < 12 : b == 12) && !found; b++)
                for (int c = (pc == 3 ? b + 1 : 12); (pc == 3 ? c < 12 : c == 12) && !found; c++) {
                    uint32_t m = (1u << a);
                    if (pc >= 2) m |= (1u << b);
                    if (pc == 3) m |= (1u << c);
                    uint32_t v1 = (m >> 4) & 15u;
                    uint32_t v2 = 0;
                    for (int j = 0; j < 4; j++)
                        v2 |= (uint32_t)(__builtin_popcount(m & Mc[4 + j]) & 1) << j;
                    uint32_t r1 = ech_reduce(e1, n1, v1);
                    uint32_t r2 = ech_reduce(e2, n2, v2);
                    if (r1 && r2) {
                        rows[nr++] = m; e1[n1++] = r1; e2[n2++] = r2; found = true;
                    }
                }
            }
            if (!found) { rows[nr] = 1u << (4 + nr); nr++; }
        }
    }
    {   // complete to an invertible 12x12
        uint32_t ef[12]{}; int nf = 0;
        for (int i = 0; i < nr; i++) {
            uint32_t r = ech_reduce(ef, nf, rows[i]);
            if (r) ef[nf++] = r;
        }
        for (uint32_t m = 1; m < 4096u && nr < 12; m++) {
            uint32_t r = ech_reduce(ef, nf, m);
            if (r) { rows[nr++] = m; ef[nf++] = r; }
        }
    }
    uint32_t col[12]{}, rc[12]{};
    for (int j = 0; j < 12; j++) {
        uint32_t c = 0;
        for (int i = 0; i < 12; i++) c |= (uint32_t)((rows[i] >> j) & 1u) << i;
        col[j] = c;
    }
    for (int j = 0; j < 12; j++) {
        uint32_t a = 0, mc = Mc[j];
        for (int q = 0; q < 12; q++) if ((mc >> q) & 1u) a ^= col[q];
        rc[j] = a;
    }
    for (int j = 0; j < 8; j++) { P.WT[j] = col[4 + j]; P.RT[j] = rc[4 + j]; }
    for (int l = 0; l < 16; l++) {
        uint32_t aw = 0, ar = 0;
        for (int q = 0; q < 4; q++) if ((l >> q) & 1) { aw ^= col[q]; ar ^= rc[q]; }
        P.WL[l] = aw; P.RL[l] = ar;
    }
    return P;
}

constexpr CK_t build_ck() {
    CK_t ck{};
    uint32_t Acols[NLAYERS][NQ]{}, Aicol5[NQ]{};
    for (int l = 0; l < NLAYERS; l++) {
        int r = l % (NQ - 1) + 1;
        for (int q = 0; q < NQ; q++) {
            uint32_t v = 1u << q;
            for (int w = NQ - 1; w >= 0; w--) {            // A = T0∘T1∘...∘T11
                int pc = NQ - 1 - w, pt = NQ - 1 - ((w + r) % NQ);
                v ^= ((v >> pc) & 1u) << pt;
            }
            Acols[l][q] = v;
            if (l == NLAYERS - 1) {
                uint32_t u = 1u << q;
                for (int w = 0; w < NQ; w++) {             // A^-1
                    int pc = NQ - 1 - w, pt = NQ - 1 - ((w + r) % NQ);
                    u ^= ((u >> pc) & 1u) << pt;
                }
                Aicol5[q] = u;
            }
        }
    }
    uint32_t McG2[12]{}, McG3[12]{}, Mc1[12]{};
    for (int j = 0; j < 12; j++) { McG2[j] = G2f(1u << j); McG3[j] = G3f(1u << j); }
    ck.PG2 = build_pass(McG2);
    ck.PG3 = build_pass(McG3);
    for (int l = 1; l < NLAYERS; l++) {
        for (int j = 0; j < 12; j++) Mc1[j] = G3f(G2f(Acols[l - 1][j]));
        ck.P1[l] = build_pass(Mc1);
    }
    // epilogue: i(k) = A5^-1(pi'(k)), pi'(v) = G2(G3(v))
    uint32_t Mcol[NQ]{};
    for (int j = 0; j < NQ; j++) {
        uint32_t pj = G2f(G3f(1u << j));
        uint32_t M = 0;
        for (int m = 0; m < NQ; m++) if ((pj >> m) & 1u) M ^= Aicol5[m];
        Mcol[j] = M;
    }
    for (int p = 0; p < NQ; p++) {
        uint32_t s = 0;
        for (int j = 0; j < NQ; j++) s |= ((Mcol[j] >> p) & 1u) << j;
        ck.frow[p] = s;
    }
    return ck;
}
constexpr CK_t CK = build_ck();

// KIND: 1 = layer rebase, 2 = swap 0-3/8-11, 3 = swap 0-3/4-7
// Single buffer: barrier (drain prior reads) -> write -> barrier -> read.
template<int KIND, int L>
__device__ __forceinline__ void do_pass(v2f (&Z)[16], v2f* buf, int tid) {
    constexpr Pass_t P = (KIND == 1) ? CK.P1[L] : (KIND == 2) ? CK.PG2 : CK.PG3;
    uint32_t comb = 0;
    #pragma unroll
    for (int j = 0; j < 8; j++) {
        uint32_t pk = P.WT[j] | (P.RT[j] << 16);
        comb ^= (uint32_t)(-(int)((tid >> j) & 1)) & pk;
    }
    uint32_t wbase = comb & 0xFFFu, rbase = comb >> 16;
    __syncthreads();
    #pragma unroll
    for (int l = 0; l < 16; l++)
        buf[wbase ^ P.WL[l]] = Z[l];
    __syncthreads();
    #pragma unroll
    for (int l = 0; l < 16; l++)
        Z[l] = buf[rbase ^ P.RL[l]];
}

// rotation on wire W at register-local bit Q; m = (m00r, m00i, m01r, m01i),
// m10 = -m.z + i*m.w, m11 = m.x - i*m.y.  J(z) = (-z.y, z.x) => packed fma.
template<int L, int W, int Q>
__device__ __forceinline__ void reg_gate(v2f (&Z)[16], const float4* smat) {
    float4 m = smat[L * NQ + W];
    #pragma unroll
    for (int l = 0; l < 16; l++) {
        if (l & (1 << Q)) continue;
        int l2 = l | (1 << Q);
        v2f z0 = Z[l], z1 = Z[l2];
        v2f j0 = { -z0.y, z0.x };
        v2f j1 = { -z1.y, z1.x };
        Z[l]  = m.x * z0 + m.y * j0 + m.z * z1 + m.w * j1;
        Z[l2] = m.x * z1 - m.y * j1 - m.z * z0 + m.w * j0;
    }
}

template<int L>
__device__ __forceinline__ void do_layer(v2f (&Z)[16], const float4* smat,
                                         v2f* xb, int tid) {
    if constexpr (L > 0)
        do_pass<1, L>(Z, xb, tid);
    reg_gate<L, 11, 0>(Z, smat);
    reg_gate<L, 10, 1>(Z, smat);
    reg_gate<L,  9, 2>(Z, smat);
    reg_gate<L,  8, 3>(Z, smat);
    do_pass<2, L>(Z, xb, tid);
    reg_gate<L, 3, 0>(Z, smat);
    reg_gate<L, 2, 1>(Z, smat);
    reg_gate<L, 1, 2>(Z, smat);
    reg_gate<L, 0, 3>(Z, smat);
    do_pass<3, L>(Z, xb, tid);
    reg_gate<L, 7, 0>(Z, smat);
    reg_gate<L, 6, 1>(Z, smat);
    reg_gate<L, 5, 2>(Z, smat);
    reg_gate<L, 4, 3>(Z, smat);
}

__global__ __launch_bounds__(TPB) void qsim_kernel(
    const float* __restrict__ x,        // [512,12]
    const float* __restrict__ weights,  // [6,12,3]
    const float* __restrict__ Wp,       // [12]
    const float* __restrict__ bptr,     // [1]
    float* __restrict__ out)            // [512]
{
    __shared__ v2f    xb[DIM];          // 32 KB single-buffered exchange
    __shared__ float4 smat[NLAYERS * NQ];
    __shared__ float  scs[NQ], sss[NQ];
    __shared__ float  red[4];

    const int tid = threadIdx.x;
    const int b   = blockIdx.x;

    if (tid < NQ) {
        float s_, c_;
        sincosf(0.5f * x[b * NQ + tid], &s_, &c_);
        scs[tid] = c_; sss[tid] = s_;
    }
    if (tid < NLAYERS * NQ) {
        float phi   = weights[tid * 3 + 0];
        float theta = weights[tid * 3 + 1];
        float omega = weights[tid * 3 + 2];
        float st, ct; sincosf(0.5f * theta, &st, &ct);
        float sp, cp; sincosf(0.5f * (phi + omega), &sp, &cp);
        float sm, cm; sincosf(0.5f * (phi - omega), &sm, &cm);
        smat[tid] = make_float4(cp * ct, -sp * ct, -cm * st, -sm * st);
    }
    __syncthreads();

    // product-state init, identity basis: k = (tid<<4)|l, bit p <-> wire 11-p
    float base = 1.0f;
    #pragma unroll
    for (int p = 4; p < NQ; p++) {
        int w = NQ - 1 - p;
        base *= ((tid >> (p - 4)) & 1) ? sss[w] : scs[w];
    }
    v2f Z[16];
    #pragma unroll
    for (int l = 0; l < 16; l++) {
        float a = base;
        #pragma unroll
        for (int p = 0; p < 4; p++) {
            int w = NQ - 1 - p;
            a *= ((l >> p) & 1) ? sss[w] : scs[w];
        }
        Z[l].x = a; Z[l].y = 0.0f;
    }

    do_layer<0>(Z, smat, xb, tid);
    do_layer<1>(Z, smat, xb, tid);
    do_layer<2>(Z, smat, xb, tid);
    do_layer<3>(Z, smat, xb, tid);
    do_layer<4>(Z, smat, xb, tid);
    do_layer<5>(Z, smat, xb, tid);

    // expectation: coef = b + sum_p W[11-p]*(1-2*bit_p(i(k)))
    const float bv = bptr[0];
    float wb[NQ];
    #pragma unroll
    for (int p = 0; p < NQ; p++) {
        uint32_t row = CK.frow[p];
        int tp = __popc(tid & (int)(row >> 4)) & 1;
        float Wv = Wp[NQ - 1 - p];
        wb[p] = tp ? -Wv : Wv;
    }
    float acc = 0.0f;
    #pragma unroll
    for (int l = 0; l < 16; l++) {
        float coef = bv;
        #pragma unroll
        for (int p = 0; p < NQ; p++)
            coef += (__popc(l & (int)(CK.frow[p] & 15u)) & 1) ? -wb[p] : wb[p];
        acc += (Z[l].x * Z[l].x + Z[l].y * Z[l].y) * coef;
    }
    #pragma unroll
    for (int off = 32; off > 0; off >>= 1)
        acc += __shfl_down(acc, off, 64);
    if ((tid & 63) == 0) red[tid >> 6] = acc;
    __syncthreads();
    if (tid == 0) out[b] = red[0] + red[1] + red[2] + red[3];
}

extern "C" void kernel_launch(void* const* d_in, const int* in_sizes, int n_in,
                              void* d_out, int out_size, void* d_ws, size_t ws_size,
                              hipStream_t stream) {
    const float* x       = (const float*)d_in[0];
    const float* weights = (const float*)d_in[1];
    const float* W       = (const float*)d_in[2];
    const float* bptr    = (const float*)d_in[3];
    qsim_kernel<<<512, TPB, 0, stream>>>(x, weights, W, bptr, (float*)d_out);
}

// Round 7
// 93.031 us; speedup vs baseline: 1.0161x; 1.0161x over previous
//
#include <hip/hip_runtime.h>
#include <stdint.h>

#define NQ 12
#define DIM 4096
#define NLAYERS 6
#define TPB 512
#define NL 8           // amps per thread (3 local bits)

typedef float v2f __attribute__((ext_vector_type(2)));

// ---------------------------------------------------------------------------
// R7: TPB=512, 8 amps/thread => 4096 waves => 4 waves/SIMD (2x R6 TLP).
// k bits: 0..2 register-local, 3..8 lane (tid 0..5), 9..11 block-thread
// (tid 6..8). Per layer: 4 GF(2) gather passes, each + 3 register gates:
//   rebase (fold CNOT A_{l-1}, wires 11,10,9), S1 swap{0-2}{3-5} (8,7,6),
//   S2 swap{0-2}{6-8} (5,4,3), S3 swap{0-2}{9-11} (2,1,0).
// 23 passes, double-buffered 64 KB, 1 barrier/pass (parities alternate).
// Each pass gets a compile-time conflict-free LDS layout Lambda: bank-pair
// functionals (slot bits 0-3) full-rank on the lane quarter span (k bits
// 3..6) and on its M-image. Layer 5's CNOT folds into epilogue sign rows.
// ---------------------------------------------------------------------------
struct Pass_t {
    uint32_t WT[9];    // Lambda columns for thread bits (k bits 3..11)
    uint32_t WL[NL];   // Lambda image of local octet l
    uint32_t RT[9];    // (Lambda o M) columns for thread bits
    uint32_t RL[NL];   // (Lambda o M) image of local octet l
};
struct CK_t {
    Pass_t PS1, PS2, PS3;   // fixed window swaps
    Pass_t P1[NLAYERS];     // per-layer rebase (index 1..5 used)
    uint32_t frow[NQ];      // epilogue sign rows
};

constexpr uint32_t S1f(uint32_t k){ return ((k&7u)<<3) | ((k>>3)&7u) | (k & 0xFC0u); }
constexpr uint32_t S2f(uint32_t k){ return ((k&7u)<<6) | (k & 0x38u) | ((k>>6)&7u) | (k & 0xE00u); }
constexpr uint32_t S3f(uint32_t k){ return ((k&7u)<<9) | (k & 0x1F8u) | ((k>>9)&7u); }

constexpr uint32_t ech_reduce(const uint32_t* v, int n, uint32_t x){
    bool ch = true;
    while (ch) {
        ch = false;
        for (int i = 0; i < n; i++)
            if (v[i] && (x ^ v[i]) < x) { x ^= v[i]; ch = true; }
    }
    return x;
}

constexpr Pass_t build_pass(const uint32_t* Mc) {
    Pass_t P{};
    uint32_t rows[12]{}; int nr = 0;
    {   // greedy bank rows: rank 4 on {e3..e6} and on {Mc[3]..Mc[6]}
        uint32_t e1[4]{}, e2[4]{}; int n1 = 0, n2 = 0;
        for (int step = 0; step < 4; step++) {
            bool found = false;
            for (int pc = 1; pc <= 3 && !found; pc++) {
                for (int a = 0; a < 12 && !found; a++)
                for (int b = (pc >= 2 ? a + 1 : 12); (pc >= 2 ? b < 12 : b == 12) && !found; b++)
                for (int c = (pc == 3 ? b + 1 : 12); (pc == 3 ? c < 12 : c == 12) && !found; c++) {
                    uint32_t m = (1u << a);
                    if (pc >= 2) m |= (1u << b);
                    if (pc == 3) m |= (1u << c);
                    uint32_t v1 = (m >> 3) & 15u;
                    uint32_t v2 = 0;
                    for (int j = 0; j < 4; j++)
                        v2 |= (uint32_t)(__builtin_popcount(m & Mc[3 + j]) & 1) << j;
                    uint32_t r1 = ech_reduce(e1, n1, v1);
                    uint32_t r2 = ech_reduce(e2, n2, v2);
                    if (r1 && r2) {
                        rows[nr++] = m; e1[n1++] = r1; e2[n2++] = r2; found = true;
                    }
                }
            }
            if (!found) { rows[nr] = 1u << (3 + nr); nr++; }
        }
    }
    {   // complete to an invertible 12x12
        uint32_t ef[12]{}; int nf = 0;
        for (int i = 0; i < nr; i++) {
            uint32_t r = ech_reduce(ef, nf, rows[i]);
            if (r) ef[nf++] = r;
        }
        for (uint32_t m = 1; m < 4096u && nr < 12; m++) {
            uint32_t r = ech_reduce(ef, nf, m);
            if (r) { rows[nr++] = m; ef[nf++] = r; }
        }
    }
    uint32_t col[12]{}, rc[12]{};
    for (int j = 0; j < 12; j++) {
        uint32_t c = 0;
        for (int i = 0; i < 12; i++) c |= (uint32_t)((rows[i] >> j) & 1u) << i;
        col[j] = c;
    }
    for (int j = 0; j < 12; j++) {
        uint32_t a = 0, mc = Mc[j];
        for (int q = 0; q < 12; q++) if ((mc >> q) & 1u) a ^= col[q];
        rc[j] = a;
    }
    for (int j = 0; j < 9; j++) { P.WT[j] = col[3 + j]; P.RT[j] = rc[3 + j]; }
    for (int l = 0; l < NL; l++) {
        uint32_t aw = 0, ar = 0;
        for (int q = 0; q < 3; q++) if ((l >> q) & 1) { aw ^= col[q]; ar ^= rc[q]; }
        P.WL[l] = aw; P.RL[l] = ar;
    }
    return P;
}

constexpr CK_t build_ck() {
    CK_t ck{};
    uint32_t Acols[NLAYERS][NQ]{}, Aicol5[NQ]{};
    for (int l = 0; l < NLAYERS; l++) {
        int r = l % (NQ - 1) + 1;
        for (int q = 0; q < NQ; q++) {
            uint32_t v = 1u << q;
            for (int w = NQ - 1; w >= 0; w--) {            // A = T0∘T1∘...∘T11
                int pc = NQ - 1 - w, pt = NQ - 1 - ((w + r) % NQ);
                v ^= ((v >> pc) & 1u) << pt;
            }
            Acols[l][q] = v;
            if (l == NLAYERS - 1) {
                uint32_t u = 1u << q;
                for (int w = 0; w < NQ; w++) {             // A^-1
                    int pc = NQ - 1 - w, pt = NQ - 1 - ((w + r) % NQ);
                    u ^= ((u >> pc) & 1u) << pt;
                }
                Aicol5[q] = u;
            }
        }
    }
    uint32_t Mc[12]{};
    for (int j = 0; j < 12; j++) Mc[j] = S1f(1u << j);
    ck.PS1 = build_pass(Mc);
    for (int j = 0; j < 12; j++) Mc[j] = S2f(1u << j);
    ck.PS2 = build_pass(Mc);
    for (int j = 0; j < 12; j++) Mc[j] = S3f(1u << j);
    ck.PS3 = build_pass(Mc);
    for (int l = 1; l < NLAYERS; l++) {
        for (int j = 0; j < 12; j++) Mc[j] = S3f(S2f(S1f(Acols[l - 1][j])));
        ck.P1[l] = build_pass(Mc);
    }
    // epilogue: i(k) = A5^-1(pi'(k)), pi'(v) = S1(S2(S3(v)))
    uint32_t Mcol[NQ]{};
    for (int j = 0; j < NQ; j++) {
        uint32_t pj = S1f(S2f(S3f(1u << j)));
        uint32_t M = 0;
        for (int m = 0; m < NQ; m++) if ((pj >> m) & 1u) M ^= Aicol5[m];
        Mcol[j] = M;
    }
    for (int p = 0; p < NQ; p++) {
        uint32_t s = 0;
        for (int j = 0; j < NQ; j++) s |= ((Mcol[j] >> p) & 1u) << j;
        ck.frow[p] = s;
    }
    return ck;
}
constexpr CK_t CK = build_ck();

// KIND: 1 = layer rebase, 2 = S1, 3 = S2, 4 = S3. Double-buffered: 1 barrier.
template<int KIND, int L, int PAR>
__device__ __forceinline__ void do_pass(v2f (&Z)[NL], v2f* xb, int tid) {
    constexpr Pass_t P = (KIND == 1) ? CK.P1[L]
                       : (KIND == 2) ? CK.PS1
                       : (KIND == 3) ? CK.PS2 : CK.PS3;
    v2f* buf = xb + PAR * DIM;
    uint32_t comb = 0;
    #pragma unroll
    for (int j = 0; j < 9; j++) {
        uint32_t pk = P.WT[j] | (P.RT[j] << 16);
        comb ^= (uint32_t)(-(int)((tid >> j) & 1)) & pk;
    }
    uint32_t wbase = comb & 0xFFFu, rbase = comb >> 16;
    #pragma unroll
    for (int l = 0; l < NL; l++)
        buf[wbase ^ P.WL[l]] = Z[l];
    __syncthreads();
    #pragma unroll
    for (int l = 0; l < NL; l++)
        Z[l] = buf[rbase ^ P.RL[l]];
}

// rotation on wire W at register-local bit Q; m = (m00r, m00i, m01r, m01i),
// m10 = -m.z + i*m.w, m11 = m.x - i*m.y.  J(z) = (-z.y, z.x) => packed fma.
template<int L, int W, int Q>
__device__ __forceinline__ void reg_gate(v2f (&Z)[NL], const float4* smat) {
    float4 m = smat[L * NQ + W];
    #pragma unroll
    for (int l = 0; l < NL; l++) {
        if (l & (1 << Q)) continue;
        int l2 = l | (1 << Q);
        v2f z0 = Z[l], z1 = Z[l2];
        v2f j0 = { -z0.y, z0.x };
        v2f j1 = { -z1.y, z1.x };
        Z[l]  = m.x * z0 + m.y * j0 + m.z * z1 + m.w * j1;
        Z[l2] = m.x * z1 - m.y * j1 - m.z * z0 + m.w * j0;
    }
}

template<int L>
__device__ __forceinline__ void do_layer(v2f (&Z)[NL], const float4* smat,
                                         v2f* xb, int tid) {
    // pass parities: rebase=1, S1=0, S2=1, S3=0 (alternates globally)
    if constexpr (L > 0)
        do_pass<1, L, 1>(Z, xb, tid);
    reg_gate<L, 11, 0>(Z, smat);
    reg_gate<L, 10, 1>(Z, smat);
    reg_gate<L,  9, 2>(Z, smat);
    do_pass<2, L, 0>(Z, xb, tid);
    reg_gate<L, 8, 0>(Z, smat);
    reg_gate<L, 7, 1>(Z, smat);
    reg_gate<L, 6, 2>(Z, smat);
    do_pass<3, L, 1>(Z, xb, tid);
    reg_gate<L, 5, 0>(Z, smat);
    reg_gate<L, 4, 1>(Z, smat);
    reg_gate<L, 3, 2>(Z, smat);
    do_pass<4, L, 0>(Z, xb, tid);
    reg_gate<L, 2, 0>(Z, smat);
    reg_gate<L, 1, 1>(Z, smat);
    reg_gate<L, 0, 2>(Z, smat);
}

__global__ __launch_bounds__(TPB) void qsim_kernel(
    const float* __restrict__ x,        // [512,12]
    const float* __restrict__ weights,  // [6,12,3]
    const float* __restrict__ Wp,       // [12]
    const float* __restrict__ bptr,     // [1]
    float* __restrict__ out)            // [512]
{
    __shared__ v2f    xb[2 * DIM];      // 64 KB double-buffered exchange
    __shared__ float4 smat[NLAYERS * NQ];
    __shared__ float  scs[NQ], sss[NQ];
    __shared__ float  red[8];

    const int tid = threadIdx.x;
    const int b   = blockIdx.x;

    if (tid < NQ) {
        float s_, c_;
        sincosf(0.5f * x[b * NQ + tid], &s_, &c_);
        scs[tid] = c_; sss[tid] = s_;
    }
    if (tid < NLAYERS * NQ) {
        float phi   = weights[tid * 3 + 0];
        float theta = weights[tid * 3 + 1];
        float omega = weights[tid * 3 + 2];
        float st, ct; sincosf(0.5f * theta, &st, &ct);
        float sp, cp; sincosf(0.5f * (phi + omega), &sp, &cp);
        float sm, cm; sincosf(0.5f * (phi - omega), &sm, &cm);
        smat[tid] = make_float4(cp * ct, -sp * ct, -cm * st, -sm * st);
    }
    __syncthreads();

    // product-state init, identity basis: k = (tid<<3)|l, bit p <-> wire 11-p
    float base = 1.0f;
    #pragma unroll
    for (int j = 0; j < 9; j++) {
        int w = 8 - j;                  // wire of k bit 3+j
        base *= ((tid >> j) & 1) ? sss[w] : scs[w];
    }
    v2f Z[NL];
    #pragma unroll
    for (int l = 0; l < NL; l++) {
        float a = base;
        #pragma unroll
        for (int p = 0; p < 3; p++) {
            int w = NQ - 1 - p;
            a *= ((l >> p) & 1) ? sss[w] : scs[w];
        }
        Z[l].x = a; Z[l].y = 0.0f;
    }

    do_layer<0>(Z, smat, xb, tid);
    do_layer<1>(Z, smat, xb, tid);
    do_layer<2>(Z, smat, xb, tid);
    do_layer<3>(Z, smat, xb, tid);
    do_layer<4>(Z, smat, xb, tid);
    do_layer<5>(Z, smat, xb, tid);

    // expectation: coef = b + sum_p W[11-p]*(1-2*bit_p(i(k)))
    const float bv = bptr[0];
    float wb[NQ];
    #pragma unroll
    for (int p = 0; p < NQ; p++) {
        uint32_t row = CK.frow[p];
        int tp = __popc(tid & (int)(row >> 3)) & 1;
        float Wv = Wp[NQ - 1 - p];
        wb[p] = tp ? -Wv : Wv;
    }
    float acc = 0.0f;
    #pragma unroll
    for (int l = 0; l < NL; l++) {
        float coef = bv;
        #pragma unroll
        for (int p = 0; p < NQ; p++)
            coef += (__popc(l & (int)(CK.frow[p] & 7u)) & 1) ? -wb[p] : wb[p];
        acc += (Z[l].x * Z[l].x + Z[l].y * Z[l].y) * coef;
    }
    #pragma unroll
    for (int off = 32; off > 0; off >>= 1)
        acc += __shfl_down(acc, off, 64);
    if ((tid & 63) == 0) red[tid >> 6] = acc;
    __syncthreads();
    if (tid == 0) {
        float s = 0.0f;
        #pragma unroll
        for (int wv = 0; wv < TPB / 64; wv++) s += red[wv];
        out[b] = s;
    }
}

extern "C" void kernel_launch(void* const* d_in, const int* in_sizes, int n_in,
                              void* d_out, int out_size, void* d_ws, size_t ws_size,
                              hipStream_t stream) {
    const float* x       = (const float*)d_in[0];
    const float* weights = (const float*)d_in[1];
    const float* W       = (const float*)d_in[2];
    const float* bptr    = (const float*)d_in[3];
    qsim_kernel<<<512, TPB, 0, stream>>>(x, weights, W, bptr, (float*)d_out);
}